// Round 10
// baseline (268.569 us; speedup 1.0000x reference)
//
#include <hip/hip_runtime.h>
#include <hip/hip_bf16.h>
#include <stdint.h>

#define GAS __attribute__((address_space(1)))
#define LAS __attribute__((address_space(3)))

typedef __attribute__((ext_vector_type(8))) short bf16x8;
typedef __attribute__((ext_vector_type(4))) float f32x4;

struct us4 { unsigned short x, y, z, w; };

__device__ __forceinline__ void gl_lds16(const void* g, void* lds) {
  __builtin_amdgcn_global_load_lds((const GAS unsigned int*)(uintptr_t)g,
                                   (LAS unsigned int*)(uintptr_t)lds, 16, 0, 0);
}

__device__ __forceinline__ unsigned short f2bf(float f) {
  unsigned u = __float_as_uint(f);
  return (unsigned short)((u + 0x7fffu + ((u >> 16) & 1u)) >> 16);
}

// ---------------- Threefry2x32 (JAX key = (0, 42)) ----------------
__device__ __forceinline__ void threefry2x32_42(unsigned x0, unsigned x1,
                                                unsigned* o0, unsigned* o1) {
  const unsigned k0 = 0u, k1 = 42u;
  unsigned ks[3] = {k0, k1, k0 ^ k1 ^ 0x1BD11BDAu};
  x0 += ks[0]; x1 += ks[1];
  const int rot[2][4] = {{13, 15, 26, 6}, {17, 29, 16, 24}};
#pragma unroll
  for (int i = 0; i < 5; ++i) {
#pragma unroll
    for (int j = 0; j < 4; ++j) {
      int r = rot[i & 1][j];
      x0 += x1;
      x1 = (x1 << r) | (x1 >> (32 - r));
      x1 ^= x0;
    }
    x0 += ks[(i + 1) % 3];
    x1 += ks[(i + 2) % 3] + (unsigned)(i + 1);
  }
  *o0 = x0; *o1 = x1;
}

// ============ single fused kernel: {build | pool} -> grid barrier -> GEMM ============
// 768 blocks x 256 threads = exactly 3 blocks/CU x 256 CUs, all co-resident
// (lb(256,3): VGPR<=168; LDS 32KB*3 <= 160KB; 12 waves/CU <= 32).
__global__ __launch_bounds__(256, 3) void k_fused(
    const float* __restrict__ X, const float* __restrict__ rw,
    const float* __restrict__ rb, const float* __restrict__ bw,
    const float* __restrict__ base_b,
    const float* __restrict__ c0, const float* __restrict__ c1,
    const float* __restrict__ c2, const float* __restrict__ c3,
    const float* __restrict__ c4, const float* __restrict__ c5,
    float* __restrict__ out, int* __restrict__ counter,
    float* __restrict__ partial, unsigned short* __restrict__ Wbt,
    unsigned short* __restrict__ Xbf) {
  __shared__ __align__(16) char smem[32768];
  int t = threadIdx.x;
  int bid = blockIdx.x;

  // ---------------- phase 1: heterogeneous prep ----------------
  if (bid < 192) {
    // ---- build Wbt[e][j][i] = bf16(bw[j][i] + 16*(K L)[i][j]) ----
    int e = bid / 48, jc = bid % 48;
    float* KA = (float*)smem;            // [96][8]
    float* LB = (float*)(smem + 3072);   // [8][96]
    float* Kt = (float*)(smem + 6144);   // [8 p3][768 i]
    float* LtS = (float*)(smem + 30720); // [16 j][8 p3]
    for (int q = t; q < 768; q += 256) {
      int bc = q >> 3, p2 = q & 7;
      int b2 = bc / 12, cc = bc % 12;
      float s = 0.f;
#pragma unroll
      for (int p1 = 0; p1 < 8; ++p1)
        s += c0[e * 96 + cc * 8 + p1] * c1[((e * 8 + p1) * 8 + b2) * 8 + p2];
      KA[q] = s;
      int p4 = q / 96, mm = q % 96;
      int n2 = mm / 12, n3 = mm % 12;
      float s2 = 0.f;
#pragma unroll
      for (int p5 = 0; p5 < 8; ++p5)
        s2 += c4[((e * 8 + p4) * 8 + n2) * 8 + p5] * c5[(e * 8 + p5) * 12 + n3];
      LB[q] = s2;
    }
    __syncthreads();
    for (int q = t; q < 6144; q += 256) {
      int i = q >> 3, p3 = q & 7;
      int a = i / 96, bc = i % 96;
      float s = 0.f;
#pragma unroll
      for (int p2 = 0; p2 < 8; ++p2)
        s += KA[bc * 8 + p2] * c2[((e * 8 + p2) * 8 + a) * 8 + p3];
      Kt[p3 * 768 + i] = s;
    }
    if (t < 128) {
      int i = t >> 3, p3 = t & 7;
      int j = jc * 16 + i;
      int n1 = j / 96, mm = j % 96;
      float s2 = 0.f;
#pragma unroll
      for (int p4 = 0; p4 < 8; ++p4)
        s2 += c3[((e * 8 + p3) * 8 + n1) * 8 + p4] * LB[p4 * 96 + mm];
      LtS[i * 8 + p3] = s2;
    }
    __syncthreads();
    for (int idx = t; idx < 12288; idx += 256) {
      int jl = idx / 768, i = idx - jl * 768;
      int j = jc * 16 + jl;
      float s = 0.f;
#pragma unroll
      for (int p = 0; p < 8; ++p) s += Kt[p * 768 + i] * LtS[jl * 8 + p];
      float val = bw[(size_t)j * 768 + i] + 16.0f * s;
      Wbt[(size_t)e * 589824 + (size_t)j * 768 + i] = f2bf(val);
    }
  } else {
    // ---- pool: X -> bf16 + logit partials. 1024 chunks of 16 rows over
    // blocks 192..767: p<448 do chunks {p, p+576}, else chunk p. ----
    float* red = (float*)smem;  // [3][4]
    int p = bid - 192;
    int nch = (p < 448) ? 2 : 1;
    for (int ci = 0; ci < nch; ++ci) {
      int c = (ci == 0) ? p : p + 576;
      float lp0 = 0.f, lp1 = 0.f, lp2 = 0.f, lp3 = 0.f;
      if (t < 192) {
        int r0 = c * 16;
        const float* xp = X + (size_t)r0 * 768 + t * 4;
        unsigned short* xo = Xbf + (size_t)r0 * 768 + t * 4;
        float4 acc = {0.f, 0.f, 0.f, 0.f};
#pragma unroll 8
        for (int r = 0; r < 16; ++r) {
          float4 v = *reinterpret_cast<const float4*>(xp + (size_t)r * 768);
          acc.x += v.x; acc.y += v.y; acc.z += v.z; acc.w += v.w;
          us4 o;
          o.x = f2bf(v.x); o.y = f2bf(v.y); o.z = f2bf(v.z); o.w = f2bf(v.w);
          *reinterpret_cast<us4*>(xo + (size_t)r * 768) = o;
        }
        float4 w0 = *reinterpret_cast<const float4*>(rw + 0 * 768 + t * 4);
        float4 w1 = *reinterpret_cast<const float4*>(rw + 1 * 768 + t * 4);
        float4 w2 = *reinterpret_cast<const float4*>(rw + 2 * 768 + t * 4);
        float4 w3 = *reinterpret_cast<const float4*>(rw + 3 * 768 + t * 4);
        lp0 = acc.x * w0.x + acc.y * w0.y + acc.z * w0.z + acc.w * w0.w;
        lp1 = acc.x * w1.x + acc.y * w1.y + acc.z * w1.z + acc.w * w1.w;
        lp2 = acc.x * w2.x + acc.y * w2.y + acc.z * w2.z + acc.w * w2.w;
        lp3 = acc.x * w3.x + acc.y * w3.y + acc.z * w3.z + acc.w * w3.w;
      }
#pragma unroll
      for (int off = 32; off > 0; off >>= 1) {
        lp0 += __shfl_down(lp0, off);
        lp1 += __shfl_down(lp1, off);
        lp2 += __shfl_down(lp2, off);
        lp3 += __shfl_down(lp3, off);
      }
      int w = t >> 6;
      __syncthreads();
      if ((t & 63) == 0 && w < 3) {
        red[w * 4 + 0] = lp0; red[w * 4 + 1] = lp1;
        red[w * 4 + 2] = lp2; red[w * 4 + 3] = lp3;
      }
      __syncthreads();
      if (t < 4) partial[c * 4 + t] = red[0 + t] + red[4 + t] + red[8 + t];
    }
  }

  // ---------------- grid barrier (all 768 blocks co-resident) ----------------
  __syncthreads();
  if (t == 0) {
    __hip_atomic_fetch_add(counter, 1, __ATOMIC_RELEASE, __HIP_MEMORY_SCOPE_AGENT);
    while (__hip_atomic_load(counter, __ATOMIC_ACQUIRE, __HIP_MEMORY_SCOPE_AGENT) < 768) {
      __builtin_amdgcn_s_sleep(8);
    }
  }
  __syncthreads();

  // ---------------- phase 2: expert pick + MFMA GEMM ----------------
  {
    unsigned short* sA = (unsigned short*)smem;            // 128x64
    unsigned short* sB = (unsigned short*)(smem + 16384);  // 128x64
    __shared__ int sExp;
    int w = t >> 6, l = t & 63;
    int l16 = l & 15, l4 = l >> 4;

    // XCD-locality remap (768 = 8*96, bijective)
    int work = (bid & 7) * 96 + (bid >> 3);
    int mtile = work / 6, ntile = work - mtile * 6;
    int m0 = mtile * 128, n0 = ntile * 128;
    int b = mtile >> 2;  // batch

    if (t < 4) {
      float s = 0.f;
#pragma unroll
      for (int c = 0; c < 32; ++c) s += partial[(b * 32 + c) * 4 + t];
      float lg = s * (1.0f / 512.0f) + rb[t];
      int idx = b * 4 + t;
      unsigned x0, x1;
      threefry2x32_42(0u, (unsigned)idx, &x0, &x1);
      unsigned bits = x0 ^ x1;  // JAX partitionable: XOR fold of cipher block
      float u01 = __uint_as_float((bits >> 9) | 0x3f800000u) - 1.0f;
      float u = u01 * ((1.0f - 1e-6f) - 1e-6f) + 1e-6f;
      u = fmaxf(u, 1e-6f);
      float v = lg + (-logf(-logf(u)));
      int bi = t;
#pragma unroll
      for (int off = 1; off < 4; off <<= 1) {
        float vo = __shfl_xor(v, off);
        int io = __shfl_xor(bi, off);
        if (vo > v || (vo == v && io < bi)) { v = vo; bi = io; }
      }
      if (t == 0) sExp = bi;
    }
    __syncthreads();
    int e = sExp;
    const unsigned short* Wb = Wbt + (size_t)e * 589824;
    int wr = w >> 1, wc = w & 1;

    f32x4 acc[4][4];
#pragma unroll
    for (int i = 0; i < 4; ++i)
#pragma unroll
      for (int jj = 0; jj < 4; ++jj) acc[i][jj] = (f32x4)0.f;

    // T2 swizzle via pre-swizzled GLOBAL source + swizzled read (rule 21).
    int rows[4], csw[4];
#pragma unroll
    for (int q = 0; q < 4; ++q) {
      int ci = (w * 4 + q) * 64 + l;
      rows[q] = ci >> 3;
      csw[q] = ((ci & 7) * 8) ^ ((rows[q] & 7) << 3);
    }

    int xorr = (l16 & 7) << 3;  // read-side swizzle
    for (int k0 = 0; k0 < 768; k0 += 64) {
#pragma unroll
      for (int q = 0; q < 4; ++q) {
        const unsigned short* ga = Xbf + (size_t)(m0 + rows[q]) * 768 + k0 + csw[q];
        gl_lds16(ga, &sA[(w * 4 + q) * 512]);
        const unsigned short* gb = Wb + (size_t)(n0 + rows[q]) * 768 + k0 + csw[q];
        gl_lds16(gb, &sB[(w * 4 + q) * 512]);
      }
      __syncthreads();
#pragma unroll
      for (int kk = 0; kk < 2; ++kk) {
        int coff = (kk * 32 + l4 * 8) ^ xorr;
        bf16x8 af[4], bfr[4];
#pragma unroll
        for (int am = 0; am < 4; ++am)
          af[am] = *reinterpret_cast<const bf16x8*>(
              &sA[(wr * 64 + am * 16 + l16) * 64 + coff]);
#pragma unroll
        for (int bn = 0; bn < 4; ++bn)
          bfr[bn] = *reinterpret_cast<const bf16x8*>(
              &sB[(wc * 64 + bn * 16 + l16) * 64 + coff]);
        // Swapped operands: reg-dim = n (coalesced stores), lane-dim = m.
#pragma unroll
        for (int am = 0; am < 4; ++am)
#pragma unroll
          for (int bn = 0; bn < 4; ++bn)
            acc[am][bn] = __builtin_amdgcn_mfma_f32_16x16x32_bf16(
                bfr[bn], af[am], acc[am][bn], 0, 0, 0);
      }
      __syncthreads();
    }

    // epilogue: n = n0 + wc*64 + bn*16 + l4*4 + r, m = m0 + wr*64 + am*16 + l16
    f32x4 bb4[4];
#pragma unroll
    for (int bn = 0; bn < 4; ++bn)
      bb4[bn] = *reinterpret_cast<const f32x4*>(base_b + n0 + wc * 64 + bn * 16 + l4 * 4);
#pragma unroll
    for (int am = 0; am < 4; ++am) {
      int m = m0 + wr * 64 + am * 16 + l16;
      float* op = out + (size_t)m * 768 + n0 + wc * 64 + l4 * 4;
#pragma unroll
      for (int bn = 0; bn < 4; ++bn) {
        f32x4 v = acc[am][bn] + bb4[bn];
        __builtin_nontemporal_store(v, reinterpret_cast<f32x4*>(op + bn * 16));
      }
    }
  }
}

extern "C" void kernel_launch(void* const* d_in, const int* in_sizes, int n_in,
                              void* d_out, int out_size, void* d_ws, size_t ws_size,
                              hipStream_t stream) {
  const float* X  = (const float*)d_in[0];
  const float* rw = (const float*)d_in[1];
  const float* rb = (const float*)d_in[2];
  const float* bw = (const float*)d_in[3];
  const float* bb = (const float*)d_in[4];
  const float* c0 = (const float*)d_in[5];
  const float* c1 = (const float*)d_in[6];
  const float* c2 = (const float*)d_in[7];
  const float* c3 = (const float*)d_in[8];
  const float* c4 = (const float*)d_in[9];
  const float* c5 = (const float*)d_in[10];
  float* out = (float*)d_out;

  char* ws = (char*)d_ws;
  int* counter        = (int*)(ws + 0);                   // 4 B, zeroed below
  float* partial      = (float*)(ws + 4096);              // 1024*4*4 = 16 KB
  unsigned short* Wbt = (unsigned short*)(ws + 262144);   // 4.5 MB
  unsigned short* Xbf = (unsigned short*)(ws + 4980736);  // 24 MB

  hipMemsetAsync(counter, 0, 4, stream);  // graph-legal; re-zeroed every replay
  k_fused<<<768, 256, 0, stream>>>(X, rw, rb, bw, bb, c0, c1, c2, c3, c4, c5,
                                   out, counter, partial, Wbt, Xbf);
}

// Round 11
// 62.854 us; speedup vs baseline: 4.2729x; 4.2729x over previous
//
#include <hip/hip_runtime.h>
#include <hip/hip_bf16.h>
#include <stdint.h>

#define GAS __attribute__((address_space(1)))
#define LAS __attribute__((address_space(3)))

typedef __attribute__((ext_vector_type(8))) short bf16x8;
typedef __attribute__((ext_vector_type(4))) float f32x4;

struct us4 { unsigned short x, y, z, w; };

__device__ __forceinline__ void gl_lds16(const void* g, void* lds) {
  __builtin_amdgcn_global_load_lds((const GAS unsigned int*)(uintptr_t)g,
                                   (LAS unsigned int*)(uintptr_t)lds, 16, 0, 0);
}

__device__ __forceinline__ unsigned short f2bf(float f) {
  unsigned u = __float_as_uint(f);
  return (unsigned short)((u + 0x7fffu + ((u >> 16) & 1u)) >> 16);
}

// ---------------- Threefry2x32 (JAX key = (0, 42)) ----------------
__device__ __forceinline__ void threefry2x32_42(unsigned x0, unsigned x1,
                                                unsigned* o0, unsigned* o1) {
  const unsigned k0 = 0u, k1 = 42u;
  unsigned ks[3] = {k0, k1, k0 ^ k1 ^ 0x1BD11BDAu};
  x0 += ks[0]; x1 += ks[1];
  const int rot[2][4] = {{13, 15, 26, 6}, {17, 29, 16, 24}};
#pragma unroll
  for (int i = 0; i < 5; ++i) {
#pragma unroll
    for (int j = 0; j < 4; ++j) {
      int r = rot[i & 1][j];
      x0 += x1;
      x1 = (x1 << r) | (x1 >> (32 - r));
      x1 ^= x0;
    }
    x0 += ks[(i + 1) % 3];
    x1 += ks[(i + 2) % 3] + (unsigned)(i + 1);
  }
  *o0 = x0; *o1 = x1;
}

// ========== kernel A: heterogeneous — blocks 0..191 build Wbt, 192..703 pool ==========
__global__ __launch_bounds__(256) void k_prep(
    const float* __restrict__ X, const float* __restrict__ rw,
    const float* __restrict__ bw,
    const float* __restrict__ c0, const float* __restrict__ c1,
    const float* __restrict__ c2, const float* __restrict__ c3,
    const float* __restrict__ c4, const float* __restrict__ c5,
    unsigned short* __restrict__ Xbf, float* __restrict__ partial,
    unsigned short* __restrict__ Wbt) {
  __shared__ __align__(16) char smem[31232];
  int t = threadIdx.x;
  int bid = blockIdx.x;

  if (bid < 192) {
    // ---- build Wbt[e][j][i] = bf16(bw[j][i] + 16*(K L)[i][j]) ----
    int e = bid / 48, jc = bid % 48;
    float* KA = (float*)smem;            // [96][8]
    float* LB = (float*)(smem + 3072);   // [8][96]
    float* Kt = (float*)(smem + 6144);   // [8 p3][768 i]
    float* LtS = (float*)(smem + 30720); // [16 j][8 p3]
    for (int q = t; q < 768; q += 256) {
      int bc = q >> 3, p2 = q & 7;
      int b2 = bc / 12, cc = bc % 12;
      float s = 0.f;
#pragma unroll
      for (int p1 = 0; p1 < 8; ++p1)
        s += c0[e * 96 + cc * 8 + p1] * c1[((e * 8 + p1) * 8 + b2) * 8 + p2];
      KA[q] = s;
      int p4 = q / 96, mm = q % 96;
      int n2 = mm / 12, n3 = mm % 12;
      float s2 = 0.f;
#pragma unroll
      for (int p5 = 0; p5 < 8; ++p5)
        s2 += c4[((e * 8 + p4) * 8 + n2) * 8 + p5] * c5[(e * 8 + p5) * 12 + n3];
      LB[q] = s2;
    }
    __syncthreads();
    for (int q = t; q < 6144; q += 256) {
      int i = q >> 3, p3 = q & 7;
      int a = i / 96, bc = i % 96;
      float s = 0.f;
#pragma unroll
      for (int p2 = 0; p2 < 8; ++p2)
        s += KA[bc * 8 + p2] * c2[((e * 8 + p2) * 8 + a) * 8 + p3];
      Kt[p3 * 768 + i] = s;
    }
    if (t < 128) {
      int i = t >> 3, p3 = t & 7;
      int j = jc * 16 + i;
      int n1 = j / 96, mm = j % 96;
      float s2 = 0.f;
#pragma unroll
      for (int p4 = 0; p4 < 8; ++p4)
        s2 += c3[((e * 8 + p3) * 8 + n1) * 8 + p4] * LB[p4 * 96 + mm];
      LtS[i * 8 + p3] = s2;
    }
    __syncthreads();
    for (int idx = t; idx < 12288; idx += 256) {
      int jl = idx / 768, i = idx - jl * 768;
      int j = jc * 16 + jl;
      float s = 0.f;
#pragma unroll
      for (int p = 0; p < 8; ++p) s += Kt[p * 768 + i] * LtS[jl * 8 + p];
      float val = bw[(size_t)j * 768 + i] + 16.0f * s;
      Wbt[(size_t)e * 589824 + (size_t)j * 768 + i] = f2bf(val);
    }
  } else {
    // ---- pool: X -> bf16 + logit partials; 512 chunks of 32 rows ----
    float* red = (float*)smem;  // [3][4]
    int p = bid - 192;
    int r0 = p * 32;
    float lp0 = 0.f, lp1 = 0.f, lp2 = 0.f, lp3 = 0.f;
    if (t < 192) {
      const float* xp = X + (size_t)r0 * 768 + t * 4;
      unsigned short* xo = Xbf + (size_t)r0 * 768 + t * 4;
      float4 acc = {0.f, 0.f, 0.f, 0.f};
#pragma unroll 8
      for (int r = 0; r < 32; ++r) {
        float4 v = *reinterpret_cast<const float4*>(xp + (size_t)r * 768);
        acc.x += v.x; acc.y += v.y; acc.z += v.z; acc.w += v.w;
        us4 o;
        o.x = f2bf(v.x); o.y = f2bf(v.y); o.z = f2bf(v.z); o.w = f2bf(v.w);
        *reinterpret_cast<us4*>(xo + (size_t)r * 768) = o;
      }
      float4 w0 = *reinterpret_cast<const float4*>(rw + 0 * 768 + t * 4);
      float4 w1 = *reinterpret_cast<const float4*>(rw + 1 * 768 + t * 4);
      float4 w2 = *reinterpret_cast<const float4*>(rw + 2 * 768 + t * 4);
      float4 w3 = *reinterpret_cast<const float4*>(rw + 3 * 768 + t * 4);
      lp0 = acc.x * w0.x + acc.y * w0.y + acc.z * w0.z + acc.w * w0.w;
      lp1 = acc.x * w1.x + acc.y * w1.y + acc.z * w1.z + acc.w * w1.w;
      lp2 = acc.x * w2.x + acc.y * w2.y + acc.z * w2.z + acc.w * w2.w;
      lp3 = acc.x * w3.x + acc.y * w3.y + acc.z * w3.z + acc.w * w3.w;
    }
#pragma unroll
    for (int off = 32; off > 0; off >>= 1) {
      lp0 += __shfl_down(lp0, off);
      lp1 += __shfl_down(lp1, off);
      lp2 += __shfl_down(lp2, off);
      lp3 += __shfl_down(lp3, off);
    }
    int w = t >> 6;
    if ((t & 63) == 0 && w < 3) {
      red[w * 4 + 0] = lp0; red[w * 4 + 1] = lp1;
      red[w * 4 + 2] = lp2; red[w * 4 + 3] = lp3;
    }
    __syncthreads();
    if (t < 4) partial[p * 4 + t] = red[0 + t] + red[4 + t] + red[8 + t];
  }
}

// ========== kernel B: per-wave expert pick + MFMA GEMM (BK=32 dbuf, 1 barrier/iter) ====
// C[t, j] = sum_k Xbf[t, k] * Wbt[e][j][k] + base_b[j]
__global__ __launch_bounds__(256, 4) void k_gemm(
    const unsigned short* __restrict__ Xbf,  // [16384][768]
    const unsigned short* __restrict__ Wbt,  // [4][768][768] (N-major)
    const float* __restrict__ partial,       // [512][4]
    const float* __restrict__ rb,            // [4]
    const float* __restrict__ base_b,        // [768]
    float* __restrict__ out)                 // [16384][768]
{
  __shared__ unsigned short sA[2][4096];  // [buf][128 rows x 32 k]
  __shared__ unsigned short sB[2][4096];
  int t = threadIdx.x;
  int w = t >> 6, l = t & 63;
  int l16 = l & 15, l4 = l >> 4;

  // XCD-locality remap (768 = 8*96, bijective)
  int bid = blockIdx.x;
  int work = (bid & 7) * 96 + (bid >> 3);
  int mtile = work / 6, ntile = work - mtile * 6;
  int m0 = mtile * 128, n0 = ntile * 128;
  int b = mtile >> 2;  // batch

  // --- per-wave expert pick (lanes 0..3 of each wave; no block barrier) ---
  int bi = 0;
  {
    float v = -1e30f;
    if (l < 4) {
      float s = 0.f;
#pragma unroll
      for (int c = 0; c < 16; ++c) s += partial[(b * 16 + c) * 4 + l];
      float lg = s * (1.0f / 512.0f) + rb[l];
      int idx = b * 4 + l;
      unsigned x0, x1;
      threefry2x32_42(0u, (unsigned)idx, &x0, &x1);
      unsigned bits = x0 ^ x1;  // JAX partitionable: XOR fold of cipher block
      float u01 = __uint_as_float((bits >> 9) | 0x3f800000u) - 1.0f;
      float u = u01 * ((1.0f - 1e-6f) - 1e-6f) + 1e-6f;
      u = fmaxf(u, 1e-6f);
      v = lg + (-logf(-logf(u)));
      bi = l;
#pragma unroll
      for (int off = 1; off < 4; off <<= 1) {
        float vo = __shfl_xor(v, off);
        int io = __shfl_xor(bi, off);
        if (vo > v || (vo == v && io < bi)) { v = vo; bi = io; }
      }
    }
    bi = __shfl(bi, 0);  // wave-broadcast lane 0's winner
  }
  const unsigned short* Wb = Wbt + (size_t)bi * 589824;
  int wr = w >> 1, wc = w & 1;

  f32x4 acc[4][4];
#pragma unroll
  for (int i = 0; i < 4; ++i)
#pragma unroll
    for (int jj = 0; jj < 4; ++jj) acc[i][jj] = (f32x4)0.f;

  // Staging geometry: per buffer, A = 128 rows x 32 k (8 KB) = 512 x 16B slots.
  // ci = (w*2+q)*64 + l, row = ci>>2, slot = ci&3.
  // Swizzle (both-sides, rule 21): stored slot holds global k-elems
  //   (slot ^ ((row>>1)&3))*8  -> read slot = l4 ^ ((row>>1)&3). 2-way max (free).
  int rows[2], ksw[2];
#pragma unroll
  for (int q = 0; q < 2; ++q) {
    int ci = (w * 2 + q) * 64 + l;
    rows[q] = ci >> 2;
    int slot = ci & 3;
    ksw[q] = (slot ^ ((rows[q] >> 1) & 3)) * 8;
  }

#define STAGE(bufi, k0)                                                        \
  {                                                                            \
    _Pragma("unroll") for (int q = 0; q < 2; ++q) {                            \
      int ci = (w * 2 + q) * 64 + l;                                           \
      const unsigned short* ga =                                               \
          Xbf + (size_t)(m0 + rows[q]) * 768 + (k0) + ksw[q];                  \
      gl_lds16(ga, &sA[bufi][ci * 8]);                                         \
      const unsigned short* gb =                                               \
          Wb + (size_t)(n0 + rows[q]) * 768 + (k0) + ksw[q];                   \
      gl_lds16(gb, &sB[bufi][ci * 8]);                                         \
    }                                                                          \
  }

  STAGE(0, 0);
  __syncthreads();  // vmcnt(0) drain: buf0 ready

  for (int kt = 0; kt < 24; ++kt) {
    int cur = kt & 1;
    if (kt < 23) STAGE(cur ^ 1, (kt + 1) * 32);  // prefetch issued BEFORE compute
    bf16x8 af[4], bfr[4];
#pragma unroll
    for (int am = 0; am < 4; ++am) {
      int row = wr * 64 + am * 16 + l16;
      int slot = l4 ^ ((row >> 1) & 3);
      af[am] = *reinterpret_cast<const bf16x8*>(&sA[cur][row * 32 + slot * 8]);
    }
#pragma unroll
    for (int bn = 0; bn < 4; ++bn) {
      int row = wc * 64 + bn * 16 + l16;
      int slot = l4 ^ ((row >> 1) & 3);
      bfr[bn] = *reinterpret_cast<const bf16x8*>(&sB[cur][row * 32 + slot * 8]);
    }
    // Swapped operands: reg-dim = n (coalesced stores), lane-dim = m.
#pragma unroll
    for (int am = 0; am < 4; ++am)
#pragma unroll
      for (int bn = 0; bn < 4; ++bn)
        acc[am][bn] = __builtin_amdgcn_mfma_f32_16x16x32_bf16(
            bfr[bn], af[am], acc[am][bn], 0, 0, 0);
    __syncthreads();  // single barrier/iter: readers done + prefetch drained
  }
#undef STAGE

  // epilogue: n = n0 + wc*64 + bn*16 + l4*4 + r, m = m0 + wr*64 + am*16 + l16
  f32x4 bb4[4];
#pragma unroll
  for (int bn = 0; bn < 4; ++bn)
    bb4[bn] = *reinterpret_cast<const f32x4*>(base_b + n0 + wc * 64 + bn * 16 + l4 * 4);
#pragma unroll
  for (int am = 0; am < 4; ++am) {
    int m = m0 + wr * 64 + am * 16 + l16;
    float* op = out + (size_t)m * 768 + n0 + wc * 64 + l4 * 4;
#pragma unroll
    for (int bn = 0; bn < 4; ++bn) {
      f32x4 v = acc[am][bn] + bb4[bn];
      __builtin_nontemporal_store(v, reinterpret_cast<f32x4*>(op + bn * 16));
    }
  }
}

extern "C" void kernel_launch(void* const* d_in, const int* in_sizes, int n_in,
                              void* d_out, int out_size, void* d_ws, size_t ws_size,
                              hipStream_t stream) {
  const float* X  = (const float*)d_in[0];
  const float* rw = (const float*)d_in[1];
  const float* rb = (const float*)d_in[2];
  const float* bw = (const float*)d_in[3];
  const float* bb = (const float*)d_in[4];
  const float* c0 = (const float*)d_in[5];
  const float* c1 = (const float*)d_in[6];
  const float* c2 = (const float*)d_in[7];
  const float* c3 = (const float*)d_in[8];
  const float* c4 = (const float*)d_in[9];
  const float* c5 = (const float*)d_in[10];
  float* out = (float*)d_out;

  char* ws = (char*)d_ws;
  float* partial      = (float*)(ws + 4096);              // 512*4*4 = 8 KB
  unsigned short* Wbt = (unsigned short*)(ws + 262144);   // 4.5 MB
  unsigned short* Xbf = (unsigned short*)(ws + 4980736);  // 24 MB

  k_prep<<<704, 256, 0, stream>>>(X, rw, bw, c0, c1, c2, c3, c4, c5,
                                  Xbf, partial, Wbt);
  k_gemm<<<768, 256, 0, stream>>>(Xbf, Wbt, partial, rb, bb, out);
}

// Round 12
// 56.263 us; speedup vs baseline: 4.7734x; 1.1171x over previous
//
#include <hip/hip_runtime.h>
#include <hip/hip_bf16.h>
#include <stdint.h>

#define GAS __attribute__((address_space(1)))
#define LAS __attribute__((address_space(3)))

typedef __attribute__((ext_vector_type(8))) short bf16x8;
typedef __attribute__((ext_vector_type(4))) float f32x4;

struct us4 { unsigned short x, y, z, w; };

__device__ __forceinline__ void gl_lds16(const void* g, void* lds) {
  __builtin_amdgcn_global_load_lds((const GAS unsigned int*)(uintptr_t)g,
                                   (LAS unsigned int*)(uintptr_t)lds, 16, 0, 0);
}

__device__ __forceinline__ unsigned short f2bf(float f) {
  unsigned u = __float_as_uint(f);
  return (unsigned short)((u + 0x7fffu + ((u >> 16) & 1u)) >> 16);
}

// ---------------- Threefry2x32 (JAX key = (0, 42)) ----------------
__device__ __forceinline__ void threefry2x32_42(unsigned x0, unsigned x1,
                                                unsigned* o0, unsigned* o1) {
  const unsigned k0 = 0u, k1 = 42u;
  unsigned ks[3] = {k0, k1, k0 ^ k1 ^ 0x1BD11BDAu};
  x0 += ks[0]; x1 += ks[1];
  const int rot[2][4] = {{13, 15, 26, 6}, {17, 29, 16, 24}};
#pragma unroll
  for (int i = 0; i < 5; ++i) {
#pragma unroll
    for (int j = 0; j < 4; ++j) {
      int r = rot[i & 1][j];
      x0 += x1;
      x1 = (x1 << r) | (x1 >> (32 - r));
      x1 ^= x0;
    }
    x0 += ks[(i + 1) % 3];
    x1 += ks[(i + 2) % 3] + (unsigned)(i + 1);
  }
  *o0 = x0; *o1 = x1;
}

// ========== kernel A: heterogeneous — blocks 0..191 build Wbt, 192..703 pool ==========
__global__ __launch_bounds__(256) void k_prep(
    const float* __restrict__ X, const float* __restrict__ rw,
    const float* __restrict__ bw,
    const float* __restrict__ c0, const float* __restrict__ c1,
    const float* __restrict__ c2, const float* __restrict__ c3,
    const float* __restrict__ c4, const float* __restrict__ c5,
    unsigned short* __restrict__ Xbf, float* __restrict__ partial,
    unsigned short* __restrict__ Wbt) {
  __shared__ __align__(16) char smem[31232];
  int t = threadIdx.x;
  int bid = blockIdx.x;

  if (bid < 192) {
    // ---- build Wbt[e][j][i] = bf16(bw[j][i] + 16*(K L)[i][j]) ----
    int e = bid / 48, jc = bid % 48;
    float* KA = (float*)smem;            // [96][8]
    float* LB = (float*)(smem + 3072);   // [8][96]
    float* Kt = (float*)(smem + 6144);   // [8 p3][768 i]
    float* LtS = (float*)(smem + 30720); // [16 j][8 p3]
    for (int q = t; q < 768; q += 256) {
      int bc = q >> 3, p2 = q & 7;
      int b2 = bc / 12, cc = bc % 12;
      float s = 0.f;
#pragma unroll
      for (int p1 = 0; p1 < 8; ++p1)
        s += c0[e * 96 + cc * 8 + p1] * c1[((e * 8 + p1) * 8 + b2) * 8 + p2];
      KA[q] = s;
      int p4 = q / 96, mm = q % 96;
      int n2 = mm / 12, n3 = mm % 12;
      float s2 = 0.f;
#pragma unroll
      for (int p5 = 0; p5 < 8; ++p5)
        s2 += c4[((e * 8 + p4) * 8 + n2) * 8 + p5] * c5[(e * 8 + p5) * 12 + n3];
      LB[q] = s2;
    }
    __syncthreads();
    for (int q = t; q < 6144; q += 256) {
      int i = q >> 3, p3 = q & 7;
      int a = i / 96, bc = i % 96;
      float s = 0.f;
#pragma unroll
      for (int p2 = 0; p2 < 8; ++p2)
        s += KA[bc * 8 + p2] * c2[((e * 8 + p2) * 8 + a) * 8 + p3];
      Kt[p3 * 768 + i] = s;
    }
    if (t < 128) {
      int i = t >> 3, p3 = t & 7;
      int j = jc * 16 + i;
      int n1 = j / 96, mm = j % 96;
      float s2 = 0.f;
#pragma unroll
      for (int p4 = 0; p4 < 8; ++p4)
        s2 += c3[((e * 8 + p3) * 8 + n1) * 8 + p4] * LB[p4 * 96 + mm];
      LtS[i * 8 + p3] = s2;
    }
    __syncthreads();
    for (int idx = t; idx < 12288; idx += 256) {
      int jl = idx / 768, i = idx - jl * 768;
      int j = jc * 16 + jl;
      float s = 0.f;
#pragma unroll
      for (int p = 0; p < 8; ++p) s += Kt[p * 768 + i] * LtS[jl * 8 + p];
      float val = bw[(size_t)j * 768 + i] + 16.0f * s;
      Wbt[(size_t)e * 589824 + (size_t)j * 768 + i] = f2bf(val);
    }
  } else {
    // ---- pool: X -> bf16 + logit partials; 512 chunks of 32 rows ----
    float* red = (float*)smem;  // [3][4]
    int p = bid - 192;
    int r0 = p * 32;
    float lp0 = 0.f, lp1 = 0.f, lp2 = 0.f, lp3 = 0.f;
    if (t < 192) {
      const float* xp = X + (size_t)r0 * 768 + t * 4;
      unsigned short* xo = Xbf + (size_t)r0 * 768 + t * 4;
      float4 acc = {0.f, 0.f, 0.f, 0.f};
#pragma unroll 8
      for (int r = 0; r < 32; ++r) {
        float4 v = *reinterpret_cast<const float4*>(xp + (size_t)r * 768);
        acc.x += v.x; acc.y += v.y; acc.z += v.z; acc.w += v.w;
        us4 o;
        o.x = f2bf(v.x); o.y = f2bf(v.y); o.z = f2bf(v.z); o.w = f2bf(v.w);
        *reinterpret_cast<us4*>(xo + (size_t)r * 768) = o;
      }
      float4 w0 = *reinterpret_cast<const float4*>(rw + 0 * 768 + t * 4);
      float4 w1 = *reinterpret_cast<const float4*>(rw + 1 * 768 + t * 4);
      float4 w2 = *reinterpret_cast<const float4*>(rw + 2 * 768 + t * 4);
      float4 w3 = *reinterpret_cast<const float4*>(rw + 3 * 768 + t * 4);
      lp0 = acc.x * w0.x + acc.y * w0.y + acc.z * w0.z + acc.w * w0.w;
      lp1 = acc.x * w1.x + acc.y * w1.y + acc.z * w1.z + acc.w * w1.w;
      lp2 = acc.x * w2.x + acc.y * w2.y + acc.z * w2.z + acc.w * w2.w;
      lp3 = acc.x * w3.x + acc.y * w3.y + acc.z * w3.z + acc.w * w3.w;
    }
#pragma unroll
    for (int off = 32; off > 0; off >>= 1) {
      lp0 += __shfl_down(lp0, off);
      lp1 += __shfl_down(lp1, off);
      lp2 += __shfl_down(lp2, off);
      lp3 += __shfl_down(lp3, off);
    }
    int w = t >> 6;
    if ((t & 63) == 0 && w < 3) {
      red[w * 4 + 0] = lp0; red[w * 4 + 1] = lp1;
      red[w * 4 + 2] = lp2; red[w * 4 + 3] = lp3;
    }
    __syncthreads();
    if (t < 4) partial[p * 4 + t] = red[0 + t] + red[4 + t] + red[8 + t];
  }
}

// ========== kernel B: per-wave expert pick + MFMA GEMM (BK=64 single-buffer) ==========
// C[t, j] = sum_k Xbf[t, k] * Wbt[e][j][k] + base_b[j]
__global__ __launch_bounds__(256, 4) void k_gemm(
    const unsigned short* __restrict__ Xbf,  // [16384][768]
    const unsigned short* __restrict__ Wbt,  // [4][768][768] (N-major)
    const float* __restrict__ partial,       // [512][4]
    const float* __restrict__ rb,            // [4]
    const float* __restrict__ base_b,        // [768]
    float* __restrict__ out)                 // [16384][768]
{
  __shared__ unsigned short sA[128 * 64];
  __shared__ unsigned short sB[128 * 64];
  int t = threadIdx.x;
  int w = t >> 6, l = t & 63;
  int l16 = l & 15, l4 = l >> 4;

  // XCD-locality remap (768 = 8*96, bijective)
  int bid = blockIdx.x;
  int work = (bid & 7) * 96 + (bid >> 3);
  int mtile = work / 6, ntile = work - mtile * 6;
  int m0 = mtile * 128, n0 = ntile * 128;
  int b = mtile >> 2;  // batch

  // --- per-wave expert pick (lanes 0..3 of each wave; no block barrier) ---
  int bi = 0;
  {
    float v = -1e30f;
    if (l < 4) {
      float s = 0.f;
#pragma unroll
      for (int c = 0; c < 16; ++c) s += partial[(b * 16 + c) * 4 + l];
      float lg = s * (1.0f / 512.0f) + rb[l];
      int idx = b * 4 + l;
      unsigned x0, x1;
      threefry2x32_42(0u, (unsigned)idx, &x0, &x1);
      unsigned bits = x0 ^ x1;  // JAX partitionable: XOR fold of cipher block
      float u01 = __uint_as_float((bits >> 9) | 0x3f800000u) - 1.0f;
      float u = u01 * ((1.0f - 1e-6f) - 1e-6f) + 1e-6f;
      u = fmaxf(u, 1e-6f);
      v = lg + (-logf(-logf(u)));
      bi = l;
#pragma unroll
      for (int off = 1; off < 4; off <<= 1) {
        float vo = __shfl_xor(v, off);
        int io = __shfl_xor(bi, off);
        if (vo > v || (vo == v && io < bi)) { v = vo; bi = io; }
      }
    }
    bi = __shfl(bi, 0);  // wave-broadcast lane 0's winner
  }
  const unsigned short* Wb = Wbt + (size_t)bi * 589824;
  int wr = w >> 1, wc = w & 1;

  f32x4 acc[4][4];
#pragma unroll
  for (int i = 0; i < 4; ++i)
#pragma unroll
    for (int jj = 0; jj < 4; ++jj) acc[i][jj] = (f32x4)0.f;

  // T2 swizzle via pre-swizzled GLOBAL source + swizzled read (rule 21).
  int rows[4], csw[4];
#pragma unroll
  for (int q = 0; q < 4; ++q) {
    int ci = (w * 4 + q) * 64 + l;
    rows[q] = ci >> 3;
    csw[q] = ((ci & 7) * 8) ^ ((rows[q] & 7) << 3);
  }

  int xorr = (l16 & 7) << 3;  // read-side swizzle
  for (int k0 = 0; k0 < 768; k0 += 64) {
#pragma unroll
    for (int q = 0; q < 4; ++q) {
      const unsigned short* ga = Xbf + (size_t)(m0 + rows[q]) * 768 + k0 + csw[q];
      gl_lds16(ga, &sA[(w * 4 + q) * 512]);
      const unsigned short* gb = Wb + (size_t)(n0 + rows[q]) * 768 + k0 + csw[q];
      gl_lds16(gb, &sB[(w * 4 + q) * 512]);
    }
    __syncthreads();
#pragma unroll
    for (int kk = 0; kk < 2; ++kk) {
      int coff = (kk * 32 + l4 * 8) ^ xorr;
      bf16x8 af[4], bfr[4];
#pragma unroll
      for (int am = 0; am < 4; ++am)
        af[am] = *reinterpret_cast<const bf16x8*>(
            &sA[(wr * 64 + am * 16 + l16) * 64 + coff]);
#pragma unroll
      for (int bn = 0; bn < 4; ++bn)
        bfr[bn] = *reinterpret_cast<const bf16x8*>(
            &sB[(wc * 64 + bn * 16 + l16) * 64 + coff]);
      // Swapped operands: reg-dim = n (coalesced stores), lane-dim = m.
#pragma unroll
      for (int am = 0; am < 4; ++am)
#pragma unroll
        for (int bn = 0; bn < 4; ++bn)
          acc[am][bn] = __builtin_amdgcn_mfma_f32_16x16x32_bf16(
              bfr[bn], af[am], acc[am][bn], 0, 0, 0);
    }
    __syncthreads();
  }

  // epilogue: n = n0 + wc*64 + bn*16 + l4*4 + r, m = m0 + wr*64 + am*16 + l16
  f32x4 bb4[4];
#pragma unroll
  for (int bn = 0; bn < 4; ++bn)
    bb4[bn] = *reinterpret_cast<const f32x4*>(base_b + n0 + wc * 64 + bn * 16 + l4 * 4);
#pragma unroll
  for (int am = 0; am < 4; ++am) {
    int m = m0 + wr * 64 + am * 16 + l16;
    float* op = out + (size_t)m * 768 + n0 + wc * 64 + l4 * 4;
#pragma unroll
    for (int bn = 0; bn < 4; ++bn) {
      f32x4 v = acc[am][bn] + bb4[bn];
      *reinterpret_cast<f32x4*>(op + bn * 16) = v;  // plain store: L2 write-combining
    }
  }
}

extern "C" void kernel_launch(void* const* d_in, const int* in_sizes, int n_in,
                              void* d_out, int out_size, void* d_ws, size_t ws_size,
                              hipStream_t stream) {
  const float* X  = (const float*)d_in[0];
  const float* rw = (const float*)d_in[1];
  const float* rb = (const float*)d_in[2];
  const float* bw = (const float*)d_in[3];
  const float* bb = (const float*)d_in[4];
  const float* c0 = (const float*)d_in[5];
  const float* c1 = (const float*)d_in[6];
  const float* c2 = (const float*)d_in[7];
  const float* c3 = (const float*)d_in[8];
  const float* c4 = (const float*)d_in[9];
  const float* c5 = (const float*)d_in[10];
  float* out = (float*)d_out;

  char* ws = (char*)d_ws;
  float* partial      = (float*)(ws + 4096);              // 512*4*4 = 8 KB
  unsigned short* Wbt = (unsigned short*)(ws + 262144);   // 4.5 MB
  unsigned short* Xbf = (unsigned short*)(ws + 4980736);  // 24 MB

  k_prep<<<704, 256, 0, stream>>>(X, rw, bw, c0, c1, c2, c3, c4, c5,
                                  Xbf, partial, Wbt);
  k_gemm<<<768, 256, 0, stream>>>(Xbf, Wbt, partial, rb, bb, out);
}